// Round 7
// baseline (157.797 us; speedup 1.0000x reference)
//
#include <hip/hip_runtime.h>

#define BATCH 4
#define SEQ 4096
#define IND 512
#define DH 64

typedef __attribute__((ext_vector_type(8))) _Float16 f16x8;
typedef __attribute__((ext_vector_type(4))) _Float16 f16x4;
typedef __attribute__((ext_vector_type(2))) _Float16 f16x2;
typedef __attribute__((ext_vector_type(4))) float f32x4;
typedef unsigned long long u64;
typedef unsigned int u32;

#define MFMA16(a, b, c) __builtin_amdgcn_mfma_f32_16x16x32_f16(a, b, c, 0, 0, 0)

// ---- Kernel 0: transposed bit-pack, qw-major: bitsT[qw][key] bit j = mask[qw*64+j][key] ----
__global__ __launch_bounds__(256) void mask_tpack_kernel(const int* __restrict__ mask,
                                                         u64* __restrict__ bitsT) {
    int wv = blockIdx.x * 4 + (threadIdx.x >> 6);  // 0..4095
    int lane = threadIdx.x & 63;
    int kb = wv & 63, qw = wv >> 6;
    int key = kb * 64 + lane;
    const int* mp = mask + (size_t)(qw * 64) * SEQ + key;
    u64 acc = 0;
#pragma unroll 16
    for (int j = 0; j < 64; ++j) {
        int m = mp[(size_t)j * SEQ];
        acc |= (u64)(m != 0) << j;
    }
    bitsT[(size_t)qw * SEQ + key] = acc;
}

// ---- Kernel 0b: weight prep: Wt[192][512] f16 (n-major, k-contig), bcat[192] f32 ----
__global__ __launch_bounds__(256) void wprep_kernel(
    const float* __restrict__ Wq, const float* __restrict__ bq,
    const float* __restrict__ Wk, const float* __restrict__ bk,
    const float* __restrict__ Wv, const float* __restrict__ bv,
    _Float16* __restrict__ Wt, float* __restrict__ bcat) {
    __shared__ float tile[64][65];
    const int bid = blockIdx.x, tid = threadIdx.x;
    const int mat = bid >> 3, k0 = (bid & 7) * 64;
    const float* W = (mat == 0) ? Wq : ((mat == 1) ? Wk : Wv);
    const float scale = (mat == 0) ? 0.125f : 1.0f;
    if (bid == 0 && tid < 192) {
        int m2 = tid >> 6, n = tid & 63;
        const float* bb = (m2 == 0) ? bq : ((m2 == 1) ? bk : bv);
        bcat[tid] = bb[n] * ((m2 == 0) ? 0.125f : 1.0f);
    }
    const int n = tid & 63, r0 = tid >> 6;
#pragma unroll
    for (int i = 0; i < 16; ++i) {
        int r = r0 * 16 + i;
        tile[r][n] = W[(size_t)(k0 + r) * 64 + n];
    }
    __syncthreads();
    const int k = tid & 63, n0 = tid >> 6;
#pragma unroll
    for (int i = 0; i < 16; ++i) {
        int nn = n0 * 16 + i;
        Wt[(size_t)(mat * 64 + nn) * IND + k0 + k] = (_Float16)(tile[k][nn] * scale);
    }
}

// ---- Kernel 1: MFMA QKV projection. Vt stored with key-interleaved 32-blocks:
//      s' = (s & ~31) + 2*(s&15) + ((s>>4)&1)  -- matches flash's packed-P order.
__global__ __launch_bounds__(256) void qkv_kernel(const float* __restrict__ X,
    const _Float16* __restrict__ Wt, const float* __restrict__ bcat,
    _Float16* __restrict__ Qh, _Float16* __restrict__ Kh, _Float16* __restrict__ Vt) {
    const int tid = threadIdx.x;
    const int w = tid >> 6, lane = tid & 63, l15 = lane & 15, g = lane >> 4;
    const int m0 = (blockIdx.x * 4 + w) * 16;
    const float* Xr = X + (size_t)(m0 + l15) * IND + g * 8;

    f32x4 acc[12];
#pragma unroll
    for (int nt = 0; nt < 12; ++nt) acc[nt] = (f32x4){0.f, 0.f, 0.f, 0.f};

#pragma unroll 4
    for (int kc = 0; kc < 16; ++kc) {
        float4 x0 = *(const float4*)(Xr + kc * 32);
        float4 x1 = *(const float4*)(Xr + kc * 32 + 4);
        f16x8 a;
        a[0] = (_Float16)x0.x; a[1] = (_Float16)x0.y; a[2] = (_Float16)x0.z; a[3] = (_Float16)x0.w;
        a[4] = (_Float16)x1.x; a[5] = (_Float16)x1.y; a[6] = (_Float16)x1.z; a[7] = (_Float16)x1.w;
        const _Float16* Wb = Wt + (size_t)l15 * IND + kc * 32 + g * 8;
#pragma unroll
        for (int nt = 0; nt < 12; ++nt)
            acc[nt] = MFMA16(a, *(const f16x8*)(Wb + (size_t)nt * 16 * IND), acc[nt]);
    }

    const int b = m0 >> 12;
    const int sbase = (m0 & (SEQ - 1)) & ~31;          // 32-block base
    const int hi = (m0 >> 4) & 1;                      // which 16-half of the 32-block
#pragma unroll
    for (int nt = 0; nt < 12; ++nt) {
        float bias = bcat[nt * 16 + l15];
        int ncol = (nt & 3) * 16 + l15;
        if (nt < 4) {
#pragma unroll
            for (int r = 0; r < 4; ++r)
                Qh[(size_t)(m0 + g * 4 + r) * DH + ncol] = (_Float16)(acc[nt][r] + bias);
        } else if (nt < 8) {
#pragma unroll
            for (int r = 0; r < 4; ++r)
                Kh[(size_t)(m0 + g * 4 + r) * DH + ncol] = (_Float16)(acc[nt][r] + bias);
        } else {
            _Float16* vb = Vt + ((size_t)b * DH + ncol) * SEQ + sbase + hi;
#pragma unroll
            for (int r = 0; r < 4; ++r)
                vb[2 * (g * 4 + r)] = (_Float16)(acc[nt][r] + bias);  // interleaved scatter
        }
    }
}

// ---- Kernel 2: f16 MFMA flash, fixed-exponent softmax, NSPLIT-way key split ----
// Register double-buffered pipeline: V(t) issued first, then K/bits(t+1) prefetch,
// then compute(t) -> waits leave the prefetch in flight (counted vmcnt, no barriers).
template <int NSPLIT>
__global__ __launch_bounds__(256, 3) void flash_kernel(
    const _Float16* __restrict__ Qh, const _Float16* __restrict__ Kh,
    const _Float16* __restrict__ Vt, const u64* __restrict__ bitsT,
    float* __restrict__ accP, float* __restrict__ lP) {
    constexpr int KPWT = SEQ / NSPLIT;
    constexpr int NT = KPWT / 32;  // 16 for NSPLIT=8 (even)
    constexpr int SH = NSPLIT / 2;
    __shared__ __align__(16) _Float16 pbuf[4][32][40];  // packed pairs, 80B row stride

    const int tid = threadIdx.x;
    const int w = tid >> 6, lane = tid & 63, l15 = lane & 15, g = lane >> 4;
    const int bid = blockIdx.x;
    const int xcd = bid & 7, i = bid >> 3;
    const int b = xcd >> 1;                      // batch pinned to XCD pair
    const int split = (xcd & 1) * SH + (i & (SH - 1));
    const int qblk = i / SH;
    const int q0 = qblk * 128 + w * 32;
    const int k0base = split * KPWT;
    const int qw = q0 >> 6;
    const int wsh = ((w & 1) << 5) + (g << 2);

    const _Float16* Qb = Qh + (size_t)b * SEQ * DH;
    const _Float16* Kb = Kh + (size_t)b * SEQ * DH;
    const _Float16* Vb = Vt + (size_t)b * DH * SEQ;
    const u64* bitsQ = bitsT + (size_t)qw * SEQ;

    f16x8 Qa[2][2];
#pragma unroll
    for (int mi = 0; mi < 2; ++mi)
#pragma unroll
        for (int kc = 0; kc < 2; ++kc)
            Qa[mi][kc] = *(const f16x8*)(Qb + (size_t)(q0 + mi * 16 + l15) * DH + kc * 32 + g * 8);

    f32x4 O[2][4];
    float lsum[8];
#pragma unroll
    for (int mi = 0; mi < 2; ++mi)
#pragma unroll
        for (int nd = 0; nd < 4; ++nd) O[mi][nd] = (f32x4){0.f, 0.f, 0.f, 0.f};
#pragma unroll
    for (int j = 0; j < 8; ++j) lsum[j] = 0.f;

    f16x8 KfA[2][2], KfB[2][2];
    u64 bwA0, bwA1, bwB0, bwB1;

    auto loadK = [&](f16x8 (&KF)[2][2], u64& B0, u64& B1, int k0) {
#pragma unroll
        for (int nt = 0; nt < 2; ++nt)
#pragma unroll
            for (int kc = 0; kc < 2; ++kc)
                KF[nt][kc] = *(const f16x8*)(Kb + (size_t)(k0 + nt * 16 + l15) * DH + kc * 32 + g * 8);
        B0 = bitsQ[k0 + l15];
        B1 = bitsQ[k0 + 16 + l15];
    };
    auto loadV = [&](f16x8 (&VF)[4], int k0) {
#pragma unroll
        for (int nd = 0; nd < 4; ++nd)
            VF[nd] = *(const f16x8*)(Vb + (size_t)(nd * 16 + l15) * SEQ + k0 + g * 8);
    };
    auto compute = [&](const f16x8 (&KF)[2][2], const f16x8 (&VF)[4], u64 B0, u64 B1) {
        u32 ms0 = (u32)(B0 >> wsh), ms1 = (u32)(B1 >> wsh);
#pragma unroll
        for (int mi = 0; mi < 2; ++mi) {
            f32x4 c0 = {0.f, 0.f, 0.f, 0.f}, c1 = {0.f, 0.f, 0.f, 0.f};
            c0 = MFMA16(Qa[mi][0], KF[0][0], c0);
            c0 = MFMA16(Qa[mi][1], KF[0][1], c0);
            c1 = MFMA16(Qa[mi][0], KF[1][0], c1);
            c1 = MFMA16(Qa[mi][1], KF[1][1], c1);
#pragma unroll
            for (int r = 0; r < 4; ++r) {
                // masked -> score 1e-6 ~ 0 -> p = exp(0) = 1.0
                float s0 = ((ms0 >> (mi * 16 + r)) & 1u) ? c0[r] : 0.0f;
                float s1 = ((ms1 >> (mi * 16 + r)) & 1u) ? c1[r] : 0.0f;
                float p0 = __expf(s0);
                float p1 = __expf(s1);
                lsum[mi * 4 + r] += p0 + p1;
                f16x2 pp;
                pp[0] = (_Float16)p0;
                pp[1] = (_Float16)p1;
                *(f16x2*)&pbuf[w][mi * 16 + 4 * g + r][2 * l15] = pp;  // one ds_write_b32
            }
        }
#pragma unroll
        for (int mi = 0; mi < 2; ++mi) {
            f16x8 Pa = *(const f16x8*)&pbuf[w][mi * 16 + l15][g * 8];
#pragma unroll
            for (int nd = 0; nd < 4; ++nd) O[mi][nd] = MFMA16(Pa, VF[nd], O[mi][nd]);
        }
    };

    loadK(KfA, bwA0, bwA1, k0base);
#pragma unroll 1
    for (int t = 0; t + 2 < NT; t += 2) {
        f16x8 VfA[4], VfB[4];
        loadV(VfA, k0base + t * 32);                       // V first (so its wait keeps
        loadK(KfB, bwB0, bwB1, k0base + (t + 1) * 32);     //  the K prefetch in flight)
        compute(KfA, VfA, bwA0, bwA1);
        loadV(VfB, k0base + (t + 1) * 32);
        loadK(KfA, bwA0, bwA1, k0base + (t + 2) * 32);
        compute(KfB, VfB, bwB0, bwB1);
    }
    {   // tail: tiles NT-2, NT-1
        f16x8 VfA[4], VfB[4];
        loadV(VfA, k0base + (NT - 2) * 32);
        loadK(KfB, bwB0, bwB1, k0base + (NT - 1) * 32);
        compute(KfA, VfA, bwA0, bwA1);
        loadV(VfB, k0base + (NT - 1) * 32);
        compute(KfB, VfB, bwB0, bwB1);
    }

#pragma unroll
    for (int j = 0; j < 8; ++j) {
        float v = lsum[j];
        v += __shfl_xor(v, 1);
        v += __shfl_xor(v, 2);
        v += __shfl_xor(v, 4);
        v += __shfl_xor(v, 8);
        lsum[j] = v;
    }
    float* accB = accP + ((size_t)split * BATCH + b) * SEQ * DH;
    float* lB = lP + ((size_t)split * BATCH + b) * SEQ;
    if (l15 == 0) {
#pragma unroll
        for (int mi = 0; mi < 2; ++mi)
#pragma unroll
            for (int r = 0; r < 4; ++r)
                lB[q0 + mi * 16 + 4 * g + r] = lsum[mi * 4 + r];
    }
#pragma unroll
    for (int mi = 0; mi < 2; ++mi)
#pragma unroll
        for (int nd = 0; nd < 4; ++nd)
#pragma unroll
            for (int r = 0; r < 4; ++r)
                accB[(size_t)(q0 + mi * 16 + 4 * g + r) * DH + nd * 16 + l15] = O[mi][nd][r];
}

// ---- Kernel 3: combine key-splits: out = sum(acc)/sum(l) ----
template <int NSPLIT>
__global__ __launch_bounds__(256) void reduce_kernel(const float* __restrict__ accP,
                                                     const float* __restrict__ lP,
                                                     float* __restrict__ out) {
    int idx = blockIdx.x * 256 + threadIdx.x;
    int bq = idx >> 6, d = idx & 63;
    float a = 0.f, l = 0.f;
#pragma unroll
    for (int s = 0; s < NSPLIT; ++s) {
        a += accP[((size_t)s * BATCH * SEQ + bq) * DH + d];
        l += lP[(size_t)s * BATCH * SEQ + bq];
    }
    out[idx] = a / l;
}

extern "C" void kernel_launch(void* const* d_in, const int* in_sizes, int n_in,
                              void* d_out, int out_size, void* d_ws, size_t ws_size,
                              hipStream_t stream) {
    const float* X = (const float*)d_in[0];
    const int* mask = (const int*)d_in[1];
    const float* Wq = (const float*)d_in[2];
    const float* bq = (const float*)d_in[3];
    const float* Wk = (const float*)d_in[4];
    const float* bk = (const float*)d_in[5];
    const float* Wv = (const float*)d_in[6];
    const float* bv = (const float*)d_in[7];
    float* out = (float*)d_out;

    char* ws = (char*)d_ws;
    _Float16* Qh = (_Float16*)ws;                       // 2 MB
    _Float16* Kh = (_Float16*)(ws + (2u << 20));        // 2 MB
    _Float16* Vt = (_Float16*)(ws + (4u << 20));        // 2 MB (key-interleaved)
    u64* bitsT = (u64*)(ws + (6u << 20));               // 2 MB
    float* accP = (float*)(ws + (8u << 20));            // up to 32 MB (8 splits)
    float* lP = (float*)(ws + (40u << 20));             // 512 KB
    _Float16* Wt = (_Float16*)(ws + (41u << 20));       // 192 KB
    float* bcat = (float*)(ws + (41u << 20) + (256u << 10));  // 768 B

    wprep_kernel<<<dim3(24), dim3(256), 0, stream>>>(Wq, bq, Wk, bk, Wv, bv, Wt, bcat);
    mask_tpack_kernel<<<dim3(1024), dim3(256), 0, stream>>>(mask, bitsT);
    qkv_kernel<<<dim3(BATCH * SEQ / 64), dim3(256), 0, stream>>>(X, Wt, bcat, Qh, Kh, Vt);

    const bool big = ws_size >= ((size_t)42u << 20);  // deterministic (ws_size fixed)
    if (big) {
        flash_kernel<8><<<dim3(BATCH * 32 * 8), dim3(256), 0, stream>>>(Qh, Kh, Vt, bitsT, accP, lP);
        reduce_kernel<8><<<dim3(BATCH * SEQ * DH / 256), dim3(256), 0, stream>>>(accP, lP, out);
    } else {
        flash_kernel<4><<<dim3(BATCH * 32 * 4), dim3(256), 0, stream>>>(Qh, Kh, Vt, bitsT, accP, lP);
        reduce_kernel<4><<<dim3(BATCH * SEQ * DH / 256), dim3(256), 0, stream>>>(accP, lP, out);
    }
}

// Round 8
// 121.289 us; speedup vs baseline: 1.3010x; 1.3010x over previous
//
#include <hip/hip_runtime.h>

#define BATCH 4
#define SEQ 4096
#define IND 512
#define DH 64
#define NSPLIT 8

typedef __attribute__((ext_vector_type(8))) _Float16 f16x8;
typedef __attribute__((ext_vector_type(2))) _Float16 f16x2;
typedef __attribute__((ext_vector_type(4))) float f32x4;
typedef unsigned long long u64;
typedef unsigned int u32;

#define MFMA16(a, b, c) __builtin_amdgcn_mfma_f32_16x16x32_f16(a, b, c, 0, 0, 0)

// ---- Kernel 0: transposed bit-pack, qw-major: bitsT[qw][key] bit j = mask[qw*64+j][key] ----
// lane owns 4 consecutive keys (int4 loads -> 4x fewer VMEM instrs); wave = 256 keys x 64 q.
__global__ __launch_bounds__(256) void mask_tpack_kernel(const int* __restrict__ mask,
                                                         u64* __restrict__ bitsT) {
    int wv = blockIdx.x * 4 + (threadIdx.x >> 6);  // 0..1023
    int lane = threadIdx.x & 63;
    int qw = wv >> 4, kg = wv & 15;
    const int* mp = mask + (size_t)(qw * 64) * SEQ + kg * 256 + lane * 4;
    u64 a0 = 0, a1 = 0, a2 = 0, a3 = 0;
#pragma unroll 16
    for (int j = 0; j < 64; ++j) {
        int4 m = *(const int4*)(mp + (size_t)j * SEQ);
        a0 |= (u64)(m.x != 0) << j;
        a1 |= (u64)(m.y != 0) << j;
        a2 |= (u64)(m.z != 0) << j;
        a3 |= (u64)(m.w != 0) << j;
    }
    u64* dst = bitsT + (size_t)qw * SEQ + kg * 256 + lane * 4;
    ulonglong2 v01 = {a0, a1}, v23 = {a2, a3};
    *(ulonglong2*)(dst) = v01;
    *(ulonglong2*)(dst + 2) = v23;
}

// ---- Kernel 0b: weight prep: Wt[192][512] f16 (n-major, k-contig), bcat[192] f32 ----
__global__ __launch_bounds__(256) void wprep_kernel(
    const float* __restrict__ Wq, const float* __restrict__ bq,
    const float* __restrict__ Wk, const float* __restrict__ bk,
    const float* __restrict__ Wv, const float* __restrict__ bv,
    _Float16* __restrict__ Wt, float* __restrict__ bcat) {
    __shared__ float tile[64][65];
    const int bid = blockIdx.x, tid = threadIdx.x;
    const int mat = bid >> 3, k0 = (bid & 7) * 64;
    const float* W = (mat == 0) ? Wq : ((mat == 1) ? Wk : Wv);
    const float scale = (mat == 0) ? 0.125f : 1.0f;
    if (bid == 0 && tid < 192) {
        int m2 = tid >> 6, n = tid & 63;
        const float* bb = (m2 == 0) ? bq : ((m2 == 1) ? bk : bv);
        bcat[tid] = bb[n] * ((m2 == 0) ? 0.125f : 1.0f);
    }
    const int n = tid & 63, r0 = tid >> 6;
#pragma unroll
    for (int i = 0; i < 16; ++i) {
        int r = r0 * 16 + i;
        tile[r][n] = W[(size_t)(k0 + r) * 64 + n];
    }
    __syncthreads();
    const int k = tid & 63, n0 = tid >> 6;
#pragma unroll
    for (int i = 0; i < 16; ++i) {
        int nn = n0 * 16 + i;
        Wt[(size_t)(mat * 64 + nn) * IND + k0 + k] = (_Float16)(tile[k][nn] * scale);
    }
}

// ---- Kernel 1: MFMA QKV projection. Vt stored with key-interleaved 32-blocks:
//      s' = (s & ~31) + 2*(s&15) + ((s>>4)&1)  -- matches flash's packed-P order.
__global__ __launch_bounds__(256) void qkv_kernel(const float* __restrict__ X,
    const _Float16* __restrict__ Wt, const float* __restrict__ bcat,
    _Float16* __restrict__ Qh, _Float16* __restrict__ Kh, _Float16* __restrict__ Vt) {
    const int tid = threadIdx.x;
    const int w = tid >> 6, lane = tid & 63, l15 = lane & 15, g = lane >> 4;
    const int m0 = (blockIdx.x * 4 + w) * 16;
    const float* Xr = X + (size_t)(m0 + l15) * IND + g * 8;

    f32x4 acc[12];
#pragma unroll
    for (int nt = 0; nt < 12; ++nt) acc[nt] = (f32x4){0.f, 0.f, 0.f, 0.f};

#pragma unroll 8
    for (int kc = 0; kc < 16; ++kc) {
        float4 x0 = *(const float4*)(Xr + kc * 32);
        float4 x1 = *(const float4*)(Xr + kc * 32 + 4);
        f16x8 a;
        a[0] = (_Float16)x0.x; a[1] = (_Float16)x0.y; a[2] = (_Float16)x0.z; a[3] = (_Float16)x0.w;
        a[4] = (_Float16)x1.x; a[5] = (_Float16)x1.y; a[6] = (_Float16)x1.z; a[7] = (_Float16)x1.w;
        const _Float16* Wb = Wt + (size_t)l15 * IND + kc * 32 + g * 8;
#pragma unroll
        for (int nt = 0; nt < 12; ++nt)
            acc[nt] = MFMA16(a, *(const f16x8*)(Wb + (size_t)nt * 16 * IND), acc[nt]);
    }

    const int b = m0 >> 12;
    const int sbase = (m0 & (SEQ - 1)) & ~31;          // 32-block base
    const int hi = (m0 >> 4) & 1;                      // which 16-half of the 32-block
#pragma unroll
    for (int nt = 0; nt < 12; ++nt) {
        float bias = bcat[nt * 16 + l15];
        int ncol = (nt & 3) * 16 + l15;
        if (nt < 4) {
#pragma unroll
            for (int r = 0; r < 4; ++r)
                Qh[(size_t)(m0 + g * 4 + r) * DH + ncol] = (_Float16)(acc[nt][r] + bias);
        } else if (nt < 8) {
#pragma unroll
            for (int r = 0; r < 4; ++r)
                Kh[(size_t)(m0 + g * 4 + r) * DH + ncol] = (_Float16)(acc[nt][r] + bias);
        } else {
            _Float16* vb = Vt + ((size_t)b * DH + ncol) * SEQ + sbase + hi;
#pragma unroll
            for (int r = 0; r < 4; ++r)
                vb[2 * (g * 4 + r)] = (_Float16)(acc[nt][r] + bias);  // interleaved scatter
        }
    }
}

// ---- Kernel 2: f16 MFMA flash, fixed-exponent softmax, 64 q-rows per wave ----
// K/V/bits loads amortized over 64 q-rows (VMEM instrs per q halved vs 32q/wave).
__global__ __launch_bounds__(256, 2) void flash_kernel(
    const _Float16* __restrict__ Qh, const _Float16* __restrict__ Kh,
    const _Float16* __restrict__ Vt, const u64* __restrict__ bitsT,
    float* __restrict__ accP, float* __restrict__ lP) {
    constexpr int KPWT = SEQ / NSPLIT;   // 512 keys per split
    constexpr int NT = KPWT / 32;        // 16 tiles
    __shared__ __align__(16) _Float16 pbuf[4][64][40];  // [wave][q][keypair], 80B row stride

    const int tid = threadIdx.x;
    const int w = tid >> 6, lane = tid & 63, l15 = lane & 15, g = lane >> 4;
    const int bid = blockIdx.x;
    const int xcd = bid & 7, i = bid >> 3;           // batch pinned to XCD pair
    const int b = xcd >> 1;
    const int split = (xcd & 1) * 4 + (i & 3);
    const int qblk = i >> 2;                          // 0..15
    const int q0 = qblk * 256 + w * 64;               // 64 q-rows per wave
    const int k0base = split * KPWT;

    const _Float16* Qb = Qh + (size_t)b * SEQ * DH;
    const _Float16* Kb = Kh + (size_t)b * SEQ * DH;
    const _Float16* Vb = Vt + (size_t)b * DH * SEQ;
    const u64* bitsQ = bitsT + (size_t)(q0 >> 6) * SEQ;  // u64 word == exactly our 64 rows

    f16x8 Qa[4][2];
#pragma unroll
    for (int mi = 0; mi < 4; ++mi)
#pragma unroll
        for (int kc = 0; kc < 2; ++kc)
            Qa[mi][kc] = *(const f16x8*)(Qb + (size_t)(q0 + mi * 16 + l15) * DH + kc * 32 + g * 8);

    f32x4 O[4][4];
    float lsum[16];
#pragma unroll
    for (int mi = 0; mi < 4; ++mi)
#pragma unroll
        for (int nd = 0; nd < 4; ++nd) O[mi][nd] = (f32x4){0.f, 0.f, 0.f, 0.f};
#pragma unroll
    for (int j = 0; j < 16; ++j) lsum[j] = 0.f;

    for (int t = 0; t < NT; ++t) {
        const int k0 = k0base + t * 32;
        f16x8 Kf[2][2], Vf[4];
#pragma unroll
        for (int nt = 0; nt < 2; ++nt)
#pragma unroll
            for (int kc = 0; kc < 2; ++kc)
                Kf[nt][kc] = *(const f16x8*)(Kb + (size_t)(k0 + nt * 16 + l15) * DH + kc * 32 + g * 8);
#pragma unroll
        for (int nd = 0; nd < 4; ++nd)
            Vf[nd] = *(const f16x8*)(Vb + (size_t)(nd * 16 + l15) * SEQ + k0 + g * 8);
        u64 bw0 = bitsQ[k0 + l15];
        u64 bw1 = bitsQ[k0 + 16 + l15];

#pragma unroll
        for (int mi = 0; mi < 4; ++mi) {
            f32x4 c0 = {0.f, 0.f, 0.f, 0.f}, c1 = {0.f, 0.f, 0.f, 0.f};
            c0 = MFMA16(Qa[mi][0], Kf[0][0], c0);
            c0 = MFMA16(Qa[mi][1], Kf[0][1], c0);
            c1 = MFMA16(Qa[mi][0], Kf[1][0], c1);
            c1 = MFMA16(Qa[mi][1], Kf[1][1], c1);
            u32 ms0 = (u32)(bw0 >> (mi * 16 + (g << 2)));
            u32 ms1 = (u32)(bw1 >> (mi * 16 + (g << 2)));
#pragma unroll
            for (int r = 0; r < 4; ++r) {
                // masked -> score 1e-6 ~ 0 -> p = exp(0) = 1.0
                float s0 = ((ms0 >> r) & 1u) ? c0[r] : 0.0f;
                float s1 = ((ms1 >> r) & 1u) ? c1[r] : 0.0f;
                float p0 = __expf(s0);
                float p1 = __expf(s1);
                lsum[mi * 4 + r] += p0 + p1;
                f16x2 pp;
                pp[0] = (_Float16)p0;
                pp[1] = (_Float16)p1;
                *(f16x2*)&pbuf[w][mi * 16 + 4 * g + r][2 * l15] = pp;  // one ds_write_b32
            }
        }
        // per-wave LDS round-trip; interleaved key order matches Vt layout
#pragma unroll
        for (int mi = 0; mi < 4; ++mi) {
            f16x8 Pa = *(const f16x8*)&pbuf[w][mi * 16 + l15][g * 8];
#pragma unroll
            for (int nd = 0; nd < 4; ++nd) O[mi][nd] = MFMA16(Pa, Vf[nd], O[mi][nd]);
        }
    }

#pragma unroll
    for (int j = 0; j < 16; ++j) {
        float v = lsum[j];
        v += __shfl_xor(v, 1);
        v += __shfl_xor(v, 2);
        v += __shfl_xor(v, 4);
        v += __shfl_xor(v, 8);
        lsum[j] = v;
    }
    float* accB = accP + ((size_t)split * BATCH + b) * SEQ * DH;
    float* lB = lP + ((size_t)split * BATCH + b) * SEQ;
    if (l15 == 0) {
#pragma unroll
        for (int mi = 0; mi < 4; ++mi)
#pragma unroll
            for (int r = 0; r < 4; ++r)
                lB[q0 + mi * 16 + 4 * g + r] = lsum[mi * 4 + r];
    }
#pragma unroll
    for (int mi = 0; mi < 4; ++mi)
#pragma unroll
        for (int nd = 0; nd < 4; ++nd)
#pragma unroll
            for (int r = 0; r < 4; ++r)
                accB[(size_t)(q0 + mi * 16 + 4 * g + r) * DH + nd * 16 + l15] = O[mi][nd][r];
}

// ---- Kernel 3: combine key-splits: out = sum(acc)/sum(l) ----
__global__ __launch_bounds__(256) void reduce_kernel(const float* __restrict__ accP,
                                                     const float* __restrict__ lP,
                                                     float* __restrict__ out) {
    int idx = blockIdx.x * 256 + threadIdx.x;
    int bq = idx >> 6, d = idx & 63;
    float a = 0.f, l = 0.f;
#pragma unroll
    for (int s = 0; s < NSPLIT; ++s) {
        a += accP[((size_t)s * BATCH * SEQ + bq) * DH + d];
        l += lP[(size_t)s * BATCH * SEQ + bq];
    }
    out[idx] = a / l;
}

extern "C" void kernel_launch(void* const* d_in, const int* in_sizes, int n_in,
                              void* d_out, int out_size, void* d_ws, size_t ws_size,
                              hipStream_t stream) {
    const float* X = (const float*)d_in[0];
    const int* mask = (const int*)d_in[1];
    const float* Wq = (const float*)d_in[2];
    const float* bq = (const float*)d_in[3];
    const float* Wk = (const float*)d_in[4];
    const float* bk = (const float*)d_in[5];
    const float* Wv = (const float*)d_in[6];
    const float* bv = (const float*)d_in[7];
    float* out = (float*)d_out;

    char* ws = (char*)d_ws;
    _Float16* Qh = (_Float16*)ws;                       // 2 MB
    _Float16* Kh = (_Float16*)(ws + (2u << 20));        // 2 MB
    _Float16* Vt = (_Float16*)(ws + (4u << 20));        // 2 MB (key-interleaved)
    u64* bitsT = (u64*)(ws + (6u << 20));               // 2 MB
    float* accP = (float*)(ws + (8u << 20));            // 32 MB (8 splits)
    float* lP = (float*)(ws + (40u << 20));             // 512 KB
    _Float16* Wt = (_Float16*)(ws + (41u << 20));       // 192 KB
    float* bcat = (float*)(ws + (41u << 20) + (256u << 10));  // 768 B

    wprep_kernel<<<dim3(24), dim3(256), 0, stream>>>(Wq, bq, Wk, bk, Wv, bv, Wt, bcat);
    mask_tpack_kernel<<<dim3(256), dim3(256), 0, stream>>>(mask, bitsT);
    qkv_kernel<<<dim3(BATCH * SEQ / 64), dim3(256), 0, stream>>>(X, Wt, bcat, Qh, Kh, Vt);
    flash_kernel<<<dim3(BATCH * 16 * NSPLIT), dim3(256), 0, stream>>>(Qh, Kh, Vt, bitsT, accP, lP);
    reduce_kernel<<<dim3(BATCH * SEQ * DH / 256), dim3(256), 0, stream>>>(accP, lP, out);
}

// Round 10
// 100.502 us; speedup vs baseline: 1.5701x; 1.2068x over previous
//
#include <hip/hip_runtime.h>

#define BATCH 4
#define SEQ 4096
#define IND 512
#define DH 64
#define NSPLIT 8

typedef __attribute__((ext_vector_type(8))) _Float16 f16x8;
typedef __attribute__((ext_vector_type(4))) _Float16 f16x4;
typedef __attribute__((ext_vector_type(2))) _Float16 f16x2;
typedef __attribute__((ext_vector_type(4))) float f32x4;
typedef unsigned long long u64;
typedef unsigned int u32;

#define MFMA16(a, b, c) __builtin_amdgcn_mfma_f32_16x16x32_f16(a, b, c, 0, 0, 0)

// ---- Kernel 0: transposed bit-pack, qw-major: bitsT[qw][key] bit j = mask[qw*64+j][key] ----
// lane owns 4 consecutive keys (int4 loads -> 4x fewer VMEM instrs); wave = 256 keys x 64 q.
__global__ __launch_bounds__(256) void mask_tpack_kernel(const int* __restrict__ mask,
                                                         u64* __restrict__ bitsT) {
    int wv = blockIdx.x * 4 + (threadIdx.x >> 6);  // 0..1023
    int lane = threadIdx.x & 63;
    int qw = wv >> 4, kg = wv & 15;
    const int* mp = mask + (size_t)(qw * 64) * SEQ + kg * 256 + lane * 4;
    u64 a0 = 0, a1 = 0, a2 = 0, a3 = 0;
#pragma unroll 16
    for (int j = 0; j < 64; ++j) {
        int4 m = *(const int4*)(mp + (size_t)j * SEQ);
        a0 |= (u64)(m.x != 0) << j;
        a1 |= (u64)(m.y != 0) << j;
        a2 |= (u64)(m.z != 0) << j;
        a3 |= (u64)(m.w != 0) << j;
    }
    u64* dst = bitsT + (size_t)qw * SEQ + kg * 256 + lane * 4;
    ulonglong2 v01 = {a0, a1}, v23 = {a2, a3};
    *(ulonglong2*)(dst) = v01;
    *(ulonglong2*)(dst + 2) = v23;
}

// ---- Kernel 0b: weight prep: Wt[192][512] f16 (n-major, k-contig), bcat[192] f32 ----
__global__ __launch_bounds__(256) void wprep_kernel(
    const float* __restrict__ Wq, const float* __restrict__ bq,
    const float* __restrict__ Wk, const float* __restrict__ bk,
    const float* __restrict__ Wv, const float* __restrict__ bv,
    _Float16* __restrict__ Wt, float* __restrict__ bcat) {
    __shared__ float tile[64][65];
    const int bid = blockIdx.x, tid = threadIdx.x;
    const int mat = bid >> 3, k0 = (bid & 7) * 64;
    const float* W = (mat == 0) ? Wq : ((mat == 1) ? Wk : Wv);
    const float scale = (mat == 0) ? 0.125f : 1.0f;
    if (bid == 0 && tid < 192) {
        int m2 = tid >> 6, n = tid & 63;
        const float* bb = (m2 == 0) ? bq : ((m2 == 1) ? bk : bv);
        bcat[tid] = bb[n] * ((m2 == 0) ? 0.125f : 1.0f);
    }
    const int n = tid & 63, r0 = tid >> 6;
#pragma unroll
    for (int i = 0; i < 16; ++i) {
        int r = r0 * 16 + i;
        tile[r][n] = W[(size_t)(k0 + r) * 64 + n];
    }
    __syncthreads();
    const int k = tid & 63, n0 = tid >> 6;
#pragma unroll
    for (int i = 0; i < 16; ++i) {
        int nn = n0 * 16 + i;
        Wt[(size_t)(mat * 64 + nn) * IND + k0 + k] = (_Float16)(tile[k][nn] * scale);
    }
}

// ---- Kernel 1: MFMA QKV projection, 3-wave blocks: wave w computes matrix w only ----
// X staged once per block into LDS as f16 (stride 520 -> 2-way banks, free);
// 1024 blocks x 3 waves = 3072 waves (12/CU). Vt key-interleaved:
//      s' = (s & ~31) + 2*(s&15) + ((s>>4)&1)  -- matches flash's packed-P order.
__global__ __launch_bounds__(192) void qkv_kernel(const float* __restrict__ X,
    const _Float16* __restrict__ Wt, const float* __restrict__ bcat,
    _Float16* __restrict__ Qh, _Float16* __restrict__ Kh, _Float16* __restrict__ Vt) {
    __shared__ __align__(16) _Float16 xs[16 * 520];  // 16 rows, stride 520 f16 (16.3 KB)
    const int tid = threadIdx.x;
    const int w = tid >> 6, lane = tid & 63, l15 = lane & 15, g = lane >> 4;
    const int m0 = blockIdx.x * 16;

    // stage X tile: 16x512 f32 -> f16, 2048 float4 across 192 threads (128 float4/row)
    const float4* src = (const float4*)(X + (size_t)m0 * IND);
#pragma unroll
    for (int u = 0; u < 11; ++u) {
        int idx = u * 192 + tid;
        if (idx < 2048) {
            float4 x = src[idx];
            int row = idx >> 7, c4 = idx & 127;  // 128 float4 per row (R9 bug: was >>5/&31)
            f16x4 h;
            h[0] = (_Float16)x.x; h[1] = (_Float16)x.y;
            h[2] = (_Float16)x.z; h[3] = (_Float16)x.w;
            *(f16x4*)&xs[row * 520 + c4 * 4] = h;
        }
    }
    __syncthreads();

    f32x4 acc[4];
#pragma unroll
    for (int nt = 0; nt < 4; ++nt) acc[nt] = (f32x4){0.f, 0.f, 0.f, 0.f};

    const _Float16* Wm = Wt + (size_t)(w * 64 + l15) * IND + g * 8;
#pragma unroll
    for (int kc = 0; kc < 16; ++kc) {
        f16x8 a = *(const f16x8*)&xs[l15 * 520 + kc * 32 + g * 8];
#pragma unroll
        for (int nt = 0; nt < 4; ++nt)
            acc[nt] = MFMA16(a, *(const f16x8*)(Wm + kc * 32 + (size_t)nt * 16 * IND), acc[nt]);
    }

    const int b = m0 >> 12;
    const int sbase = (m0 & (SEQ - 1)) & ~31;  // 32-block base
    const int hi = (m0 >> 4) & 1;              // which 16-half of the 32-block
#pragma unroll
    for (int nt = 0; nt < 4; ++nt) {
        float bias = bcat[w * 64 + nt * 16 + l15];
        int ncol = nt * 16 + l15;
        if (w == 0) {
#pragma unroll
            for (int r = 0; r < 4; ++r)
                Qh[(size_t)(m0 + g * 4 + r) * DH + ncol] = (_Float16)(acc[nt][r] + bias);
        } else if (w == 1) {
#pragma unroll
            for (int r = 0; r < 4; ++r)
                Kh[(size_t)(m0 + g * 4 + r) * DH + ncol] = (_Float16)(acc[nt][r] + bias);
        } else {
            _Float16* vb = Vt + ((size_t)b * DH + ncol) * SEQ + sbase + hi;
#pragma unroll
            for (int r = 0; r < 4; ++r)
                vb[2 * (g * 4 + r)] = (_Float16)(acc[nt][r] + bias);  // interleaved scatter
        }
    }
}

// ---- Kernel 2: f16 MFMA flash, fixed-exponent softmax, 64 q-rows per wave ----
__global__ __launch_bounds__(256, 2) void flash_kernel(
    const _Float16* __restrict__ Qh, const _Float16* __restrict__ Kh,
    const _Float16* __restrict__ Vt, const u64* __restrict__ bitsT,
    float* __restrict__ accP, float* __restrict__ lP) {
    constexpr int KPWT = SEQ / NSPLIT;   // 512 keys per split
    constexpr int NT = KPWT / 32;        // 16 tiles
    __shared__ __align__(16) _Float16 pbuf[4][64][40];  // [wave][q][keypair], 80B row stride

    const int tid = threadIdx.x;
    const int w = tid >> 6, lane = tid & 63, l15 = lane & 15, g = lane >> 4;
    const int bid = blockIdx.x;
    const int xcd = bid & 7, i = bid >> 3;           // batch pinned to XCD pair
    const int b = xcd >> 1;
    const int split = (xcd & 1) * 4 + (i & 3);
    const int qblk = i >> 2;                          // 0..15
    const int q0 = qblk * 256 + w * 64;               // 64 q-rows per wave
    const int k0base = split * KPWT;

    const _Float16* Qb = Qh + (size_t)b * SEQ * DH;
    const _Float16* Kb = Kh + (size_t)b * SEQ * DH;
    const _Float16* Vb = Vt + (size_t)b * DH * SEQ;
    const u64* bitsQ = bitsT + (size_t)(q0 >> 6) * SEQ;  // u64 word == exactly our 64 rows

    f16x8 Qa[4][2];
#pragma unroll
    for (int mi = 0; mi < 4; ++mi)
#pragma unroll
        for (int kc = 0; kc < 2; ++kc)
            Qa[mi][kc] = *(const f16x8*)(Qb + (size_t)(q0 + mi * 16 + l15) * DH + kc * 32 + g * 8);

    f32x4 O[4][4];
    float lsum[16];
#pragma unroll
    for (int mi = 0; mi < 4; ++mi)
#pragma unroll
        for (int nd = 0; nd < 4; ++nd) O[mi][nd] = (f32x4){0.f, 0.f, 0.f, 0.f};
#pragma unroll
    for (int j = 0; j < 16; ++j) lsum[j] = 0.f;

    for (int t = 0; t < NT; ++t) {
        const int k0 = k0base + t * 32;
        f16x8 Kf[2][2], Vf[4];
#pragma unroll
        for (int nt = 0; nt < 2; ++nt)
#pragma unroll
            for (int kc = 0; kc < 2; ++kc)
                Kf[nt][kc] = *(const f16x8*)(Kb + (size_t)(k0 + nt * 16 + l15) * DH + kc * 32 + g * 8);
#pragma unroll
        for (int nd = 0; nd < 4; ++nd)
            Vf[nd] = *(const f16x8*)(Vb + (size_t)(nd * 16 + l15) * SEQ + k0 + g * 8);
        u64 bw0 = bitsQ[k0 + l15];
        u64 bw1 = bitsQ[k0 + 16 + l15];

#pragma unroll
        for (int mi = 0; mi < 4; ++mi) {
            f32x4 c0 = {0.f, 0.f, 0.f, 0.f}, c1 = {0.f, 0.f, 0.f, 0.f};
            c0 = MFMA16(Qa[mi][0], Kf[0][0], c0);
            c0 = MFMA16(Qa[mi][1], Kf[0][1], c0);
            c1 = MFMA16(Qa[mi][0], Kf[1][0], c1);
            c1 = MFMA16(Qa[mi][1], Kf[1][1], c1);
            u32 ms0 = (u32)(bw0 >> (mi * 16 + (g << 2)));
            u32 ms1 = (u32)(bw1 >> (mi * 16 + (g << 2)));
#pragma unroll
            for (int r = 0; r < 4; ++r) {
                // masked -> score 1e-6 ~ 0 -> p = exp(0) = 1.0
                float s0 = ((ms0 >> r) & 1u) ? c0[r] : 0.0f;
                float s1 = ((ms1 >> r) & 1u) ? c1[r] : 0.0f;
                float p0 = __expf(s0);
                float p1 = __expf(s1);
                lsum[mi * 4 + r] += p0 + p1;
                f16x2 pp;
                pp[0] = (_Float16)p0;
                pp[1] = (_Float16)p1;
                *(f16x2*)&pbuf[w][mi * 16 + 4 * g + r][2 * l15] = pp;  // one ds_write_b32
            }
        }
        // per-wave LDS round-trip; interleaved key order matches Vt layout
#pragma unroll
        for (int mi = 0; mi < 4; ++mi) {
            f16x8 Pa = *(const f16x8*)&pbuf[w][mi * 16 + l15][g * 8];
#pragma unroll
            for (int nd = 0; nd < 4; ++nd) O[mi][nd] = MFMA16(Pa, Vf[nd], O[mi][nd]);
        }
    }

#pragma unroll
    for (int j = 0; j < 16; ++j) {
        float v = lsum[j];
        v += __shfl_xor(v, 1);
        v += __shfl_xor(v, 2);
        v += __shfl_xor(v, 4);
        v += __shfl_xor(v, 8);
        lsum[j] = v;
    }
    float* accB = accP + ((size_t)split * BATCH + b) * SEQ * DH;
    float* lB = lP + ((size_t)split * BATCH + b) * SEQ;
    if (l15 == 0) {
#pragma unroll
        for (int mi = 0; mi < 4; ++mi)
#pragma unroll
            for (int r = 0; r < 4; ++r)
                lB[q0 + mi * 16 + 4 * g + r] = lsum[mi * 4 + r];
    }
#pragma unroll
    for (int mi = 0; mi < 4; ++mi)
#pragma unroll
        for (int nd = 0; nd < 4; ++nd)
#pragma unroll
            for (int r = 0; r < 4; ++r)
                accB[(size_t)(q0 + mi * 16 + 4 * g + r) * DH + nd * 16 + l15] = O[mi][nd][r];
}

// ---- Kernel 3: combine key-splits: out = sum(acc)/sum(l) ----
__global__ __launch_bounds__(256) void reduce_kernel(const float* __restrict__ accP,
                                                     const float* __restrict__ lP,
                                                     float* __restrict__ out) {
    int idx = blockIdx.x * 256 + threadIdx.x;
    int bq = idx >> 6, d = idx & 63;
    float a = 0.f, l = 0.f;
#pragma unroll
    for (int s = 0; s < NSPLIT; ++s) {
        a += accP[((size_t)s * BATCH * SEQ + bq) * DH + d];
        l += lP[(size_t)s * BATCH * SEQ + bq];
    }
    out[idx] = a / l;
}

extern "C" void kernel_launch(void* const* d_in, const int* in_sizes, int n_in,
                              void* d_out, int out_size, void* d_ws, size_t ws_size,
                              hipStream_t stream) {
    const float* X = (const float*)d_in[0];
    const int* mask = (const int*)d_in[1];
    const float* Wq = (const float*)d_in[2];
    const float* bq = (const float*)d_in[3];
    const float* Wk = (const float*)d_in[4];
    const float* bk = (const float*)d_in[5];
    const float* Wv = (const float*)d_in[6];
    const float* bv = (const float*)d_in[7];
    float* out = (float*)d_out;

    char* ws = (char*)d_ws;
    _Float16* Qh = (_Float16*)ws;                       // 2 MB
    _Float16* Kh = (_Float16*)(ws + (2u << 20));        // 2 MB
    _Float16* Vt = (_Float16*)(ws + (4u << 20));        // 2 MB (key-interleaved)
    u64* bitsT = (u64*)(ws + (6u << 20));               // 2 MB
    float* accP = (float*)(ws + (8u << 20));            // 32 MB (8 splits)
    float* lP = (float*)(ws + (40u << 20));             // 512 KB
    _Float16* Wt = (_Float16*)(ws + (41u << 20));       // 192 KB
    float* bcat = (float*)(ws + (41u << 20) + (256u << 10));  // 768 B

    wprep_kernel<<<dim3(24), dim3(256), 0, stream>>>(Wq, bq, Wk, bk, Wv, bv, Wt, bcat);
    mask_tpack_kernel<<<dim3(256), dim3(256), 0, stream>>>(mask, bitsT);
    qkv_kernel<<<dim3(BATCH * SEQ / 16), dim3(192), 0, stream>>>(X, Wt, bcat, Qh, Kh, Vt);
    flash_kernel<<<dim3(BATCH * 16 * NSPLIT), dim3(256), 0, stream>>>(Qh, Kh, Vt, bitsT, accP, lP);
    reduce_kernel<<<dim3(BATCH * SEQ * DH / 256), dim3(256), 0, stream>>>(accP, lP, out);
}